// Round 6
// baseline (192.917 us; speedup 1.0000x reference)
//
#include <hip/hip_runtime.h>
#include <hip/hip_bf16.h>
#include <math.h>

#define B_   32
#define CI   256
#define CO   256
#define KW   7
#define NW   8
#define SQD  8
#define L_   4096

typedef __attribute__((ext_vector_type(8))) __bf16 bf16x8;
typedef __attribute__((ext_vector_type(4))) __bf16 bf16x4;
typedef __attribute__((ext_vector_type(4))) float  f32x4;

static __device__ __forceinline__ unsigned short f2bf(float f) {
    unsigned int u = __builtin_bit_cast(unsigned int, f);
    u += 0x7FFFu + ((u >> 16) & 1u);
    return (unsigned short)(u >> 16);
}
// native-cast pack: compiler emits v_cvt_pk_bf16_f32
static __device__ __forceinline__ uint2 pack4bf(float a, float b, float c, float d) {
    bf16x4 v;
    v[0] = (__bf16)a; v[1] = (__bf16)b; v[2] = (__bf16)c; v[3] = (__bf16)d;
    return __builtin_bit_cast(uint2, v);
}

// ---------------------------------------------------------------------------
// k1: mean over L (deterministic). One block per (b,i) row.
// ---------------------------------------------------------------------------
__global__ __launch_bounds__(256) void k1_mean(
        const float* __restrict__ x, float* __restrict__ pooled) {
    int row = blockIdx.x;                       // b*CI + i
    const float* p = x + (size_t)row * L_;
    int t = threadIdx.x;
    float s = 0.f;
#pragma unroll
    for (int it = 0; it < 4; ++it) {
        float4 v = *(const float4*)(p + (size_t)(t + 256 * it) * 4);
        s += v.x + v.y + v.z + v.w;
    }
    for (int m = 1; m <= 32; m <<= 1) s += __shfl_xor(s, m);
    __shared__ float wsum[4];
    if ((t & 63) == 0) wsum[t >> 6] = s;
    __syncthreads();
    if (t == 0)
        pooled[row] = (wsum[0] + wsum[1] + wsum[2] + wsum[3]) * (1.0f / L_);
}

// ---------------------------------------------------------------------------
// k2: squeeze net + gates. one block (1 wave) per sample.
// ---------------------------------------------------------------------------
__global__ __launch_bounds__(64) void k2_gates(
        const float* __restrict__ pooled,
        const float* __restrict__ w1, const float* __restrict__ b1,
        const float* __restrict__ wk, const float* __restrict__ wi,
        const float* __restrict__ wo, const float* __restrict__ wn,
        float* __restrict__ kr, float* __restrict__ inc,
        float* __restrict__ outc, float* __restrict__ nums)
{
    int b = blockIdx.x, lane = threadIdx.x;
    float pc[4];
#pragma unroll
    for (int j = 0; j < 4; ++j)
        pc[j] = pooled[b * CI + lane + 64 * j];
    float h[SQD];
#pragma unroll
    for (int s = 0; s < SQD; ++s) {
        float ps = 0.f;
#pragma unroll
        for (int j = 0; j < 4; ++j)
            ps += pc[j] * w1[(lane + 64 * j) * SQD + s];
        for (int m = 1; m <= 32; m <<= 1) ps += __shfl_xor(ps, m);
        float z = ps + b1[s];
        h[s] = 0.5f * z * (1.0f + erff(z * 0.70710678118654752f));
    }
    if (lane < KW) {
        float a = 0.f;
#pragma unroll
        for (int s = 0; s < SQD; ++s) a += h[s] * wk[s * KW + lane];
        kr[b * 8 + lane] = 1.0f / (1.0f + expf(-a));
    }
    if (lane < NW) {
        float e[NW]; float mx = -1e30f;
#pragma unroll
        for (int n = 0; n < NW; ++n) {
            float a = 0.f;
#pragma unroll
            for (int s = 0; s < SQD; ++s) a += h[s] * wn[s * NW + n];
            e[n] = a; mx = fmaxf(mx, a);
        }
        float den = 0.f;
#pragma unroll
        for (int n = 0; n < NW; ++n) den += expf(e[n] - mx);
        nums[b * NW + lane] = expf(e[lane] - mx) / den;
    }
#pragma unroll
    for (int j = 0; j < 4; ++j) {
        int c = lane + 64 * j;
        float a = 0.f, o2 = 0.f;
#pragma unroll
        for (int s = 0; s < SQD; ++s) {
            a  += h[s] * wi[s * CI + c];
            o2 += h[s] * wo[s * CO + c];
        }
        inc[b * CI + c]  = 1.0f / (1.0f + expf(-a));
        outc[b * CO + c] = 1.0f / (1.0f + expf(-o2));
    }
}

// ---------------------------------------------------------------------------
// k3: per-sample mixed weights, MFMA layout W2[b][k*8+ic][o][i%32] bf16.
// ---------------------------------------------------------------------------
__global__ __launch_bounds__(256) void k3_wgen(
        const float* __restrict__ cw,
        const float* __restrict__ kr, const float* __restrict__ inc,
        const float* __restrict__ outc, const float* __restrict__ nums,
        unsigned short* __restrict__ W2) {
    __shared__ float s_nums[B_][NW];
    __shared__ float s_kr[B_][KW];
    __shared__ float s_inc[B_][32];
    __shared__ float s_outc[B_][8];
    int t = threadIdx.x;
    int ic = blockIdx.x & 7, o0 = (blockIdx.x >> 3) * 8;
    s_nums[t >> 3][t & 7] = nums[t];
    if (t < B_ * KW) s_kr[t / KW][t % KW] = kr[(t / KW) * 8 + (t % KW)];
    for (int u = t; u < 32 * 32; u += 256) {
        int bb = u >> 5, ii = u & 31;
        s_inc[bb][ii] = inc[bb * CI + ic * 32 + ii];
    }
    for (int u = t; u < 32 * 8; u += 256) {
        int bb = u >> 3, oo = u & 7;
        s_outc[bb][oo] = outc[bb * CO + o0 + oo];
    }
    __syncthreads();
    int ii = t & 31, oo = t >> 5;
    int o = o0 + oo, i = ic * 32 + ii;
    float cwv[KW][NW];
    const float* p = cw + ((size_t)(o * CI + i)) * (KW * NW);
#pragma unroll
    for (int k = 0; k < KW; ++k)
#pragma unroll
        for (int n = 0; n < NW; ++n) cwv[k][n] = p[k * NW + n];
    for (int bb = 0; bb < B_; ++bb) {
        float gio = s_inc[bb][ii] * s_outc[bb][oo];
#pragma unroll
        for (int k = 0; k < KW; ++k) {
            float sk = 0.f;
#pragma unroll
            for (int n = 0; n < NW; ++n) sk += s_nums[bb][n] * cwv[k][n];
            float w = s_kr[bb][k] * gio * sk;
            W2[(((size_t)(bb * KW + k) * 8 + ic) * CO + o) * 32 + ii] = f2bf(w);
        }
    }
}

// ---------------------------------------------------------------------------
// k4: fused transpose + per-sample im2col GEMM (16x16x32 bf16 MFMA).
//     Block = 256 o x 256 l; 8 waves (2o x 4l), wave = 128o x 64l, acc[8][4].
//     -> LDS B-reads per step: 4 b128 (halved vs r5); A (W2) streamed
//     from L2 (8 b128/step, 4x reuse across l-waves).
//     LDS xs[262][256] bf16 (134 KB), swizzle sw(r)=(r&7)^((r>>2)&7).
//     K-loop: 56 steps, manual 2-deep register pipeline.
// ---------------------------------------------------------------------------
__global__ __launch_bounds__(512, 2) void k4_conv(
        const float* __restrict__ x,             // fp32 [B][CI][L]
        const unsigned short* __restrict__ W2,   // bf16 [B][56][CO][32]
        float* __restrict__ out) {               // [B][CO][L]
    __shared__ __align__(16) unsigned short xs[262 * 256];
    int bid = blockIdx.x;
    int wg  = (bid & 7) * 64 + (bid >> 3);       // XCD-bijective (512%8==0)
    int b = wg >> 4, l0 = (wg & 15) * 256;
    int t = threadIdx.x;
    const float* xb = x + (size_t)b * CI * L_;

    // ---- main staging: rows 3..258 (l = l0..l0+255), all 256 i ----
    {
        int ch = (t & 31) + 32 * (t >> 8);       // l-chunk 0..63
        int g  = (t >> 5) & 7;                   // i-group
#pragma unroll
        for (int it = 0; it < 8; ++it) {
            int i0 = g * 4 + it * 32;
            float4 f0 = *(const float4*)(xb + (size_t)(i0 + 0) * L_ + l0 + ch * 4);
            float4 f1 = *(const float4*)(xb + (size_t)(i0 + 1) * L_ + l0 + ch * 4);
            float4 f2 = *(const float4*)(xb + (size_t)(i0 + 2) * L_ + l0 + ch * 4);
            float4 f3 = *(const float4*)(xb + (size_t)(i0 + 3) * L_ + l0 + ch * 4);
            int u = i0 >> 3, h = (i0 >> 2) & 1;
#pragma unroll
            for (int j = 0; j < 4; ++j) {
                int r = 4 * ch + j + 3;
                uint2 w = pack4bf((&f0.x)[j], (&f1.x)[j], (&f2.x)[j], (&f3.x)[j]);
                int sw = (r & 7) ^ ((r >> 2) & 7);
                *(uint2*)(xs + r * 256 + ((u ^ sw) * 8) + h * 4) = w;
            }
        }
    }
    // ---- halo: rows 0..2 (l0-3..l0-1) and 259..261 (l0+256..l0+258) ----
    if (t < 128) {
        bool left = t < 64;
        int tt = left ? t : t - 64;
        int i0 = tt * 4;
        int gl4 = left ? l0 - 4 : l0 + 256;
        bool ok = left ? (l0 > 0) : (l0 + 256 < L_);
        float4 f[4];
#pragma unroll
        for (int d = 0; d < 4; ++d)
            f[d] = ok ? *(const float4*)(xb + (size_t)(i0 + d) * L_ + gl4)
                      : make_float4(0.f, 0.f, 0.f, 0.f);
        int u = i0 >> 3, h = (i0 >> 2) & 1;
#pragma unroll
        for (int j = 0; j < 4; ++j) {
            if (left && j == 0) continue;
            if (!left && j == 3) continue;
            int r = left ? (j - 1) : (259 + j);
            uint2 w = pack4bf((&f[0].x)[j], (&f[1].x)[j], (&f[2].x)[j], (&f[3].x)[j]);
            int sw = (r & 7) ^ ((r >> 2) & 7);
            *(uint2*)(xs + r * 256 + ((u ^ sw) * 8) + h * 4) = w;
        }
    }
    __syncthreads();

    int lane = t & 63, wid = t >> 6;
    int o_base = (wid & 1) * 128;                // 2 o-waves of 128
    int l_off  = (wid >> 1) * 64;                // 4 l-waves of 64
    int ml = lane & 15, kg = lane >> 4;

    f32x4 acc[8][4];
#pragma unroll
    for (int a = 0; a < 8; ++a)
#pragma unroll
        for (int c = 0; c < 4; ++c) acc[a][c] = (f32x4){0.f, 0.f, 0.f, 0.f};

    const unsigned short* wbase = W2 + (size_t)b * (56 * CO * 32);

    auto LOADF = [&](bf16x8 (&AF)[8], bf16x8 (&BF)[4], int S) {
        int k_ = S >> 3, icc_ = S & 7;
        const unsigned short* wkc = wbase + (size_t)S * (CO * 32);
#pragma unroll
        for (int mt = 0; mt < 8; ++mt)
            AF[mt] = *(const bf16x8*)(wkc + (o_base + mt * 16 + ml) * 32 + kg * 8);
#pragma unroll
        for (int nt = 0; nt < 4; ++nt) {
            int r = l_off + nt * 16 + ml + k_;
            int unit = (icc_ * 4 + kg) ^ ((r & 7) ^ ((r >> 2) & 7));
            BF[nt] = *(const bf16x8*)(xs + r * 256 + unit * 8);
        }
    };
    auto DOMFMA = [&](bf16x8 (&AF)[8], bf16x8 (&BF)[4]) {
        __builtin_amdgcn_s_setprio(1);
#pragma unroll
        for (int mt = 0; mt < 8; ++mt)
#pragma unroll
            for (int nt = 0; nt < 4; ++nt)
                acc[mt][nt] = __builtin_amdgcn_mfma_f32_16x16x32_bf16(
                    AF[mt], BF[nt], acc[mt][nt], 0, 0, 0);
        __builtin_amdgcn_s_setprio(0);
    };

    bf16x8 afA[8], bfA[4], afB[8], bfB[4];
    LOADF(afA, bfA, 0);
    for (int s = 0; s < 56; s += 2) {
        LOADF(afB, bfB, s + 1);
        DOMFMA(afA, bfA);
        if (s + 2 < 56) LOADF(afA, bfA, s + 2);
        DOMFMA(afB, bfB);
    }

    // epilogue: D row(o)=(lane>>4)*4+q, col(l)=lane&15
#pragma unroll
    for (int mt = 0; mt < 8; ++mt) {
        int o = o_base + mt * 16 + kg * 4;
#pragma unroll
        for (int nt = 0; nt < 4; ++nt) {
            int l = l0 + l_off + nt * 16 + ml;
            float* po = out + ((size_t)(b * CO + o)) * L_ + l;
#pragma unroll
            for (int q = 0; q < 4; ++q)
                po[(size_t)q * L_] = acc[mt][nt][q];
        }
    }
}

// ---------------------------------------------------------------------------
extern "C" void kernel_launch(void* const* d_in, const int* in_sizes, int n_in,
                              void* d_out, int out_size, void* d_ws, size_t ws_size,
                              hipStream_t stream) {
    const float* x  = (const float*)d_in[0];
    const float* cw = (const float*)d_in[1];
    const float* w1 = (const float*)d_in[2];
    const float* b1 = (const float*)d_in[3];
    const float* wk = (const float*)d_in[4];
    const float* wi = (const float*)d_in[5];
    const float* wo = (const float*)d_in[6];
    const float* wn = (const float*)d_in[7];
    float* out = (float*)d_out;

    char* ws = (char*)d_ws;
    unsigned short* W2 = (unsigned short*)(ws + 0);          // 29360128 B
    float* pooled = (float*)(ws + 29360128);
    float* kr     = (float*)(ws + 29392896);
    float* inc    = (float*)(ws + 29393920);
    float* outc   = (float*)(ws + 29426688);
    float* nums   = (float*)(ws + 29459456);

    k1_mean<<<B_ * CI, 256, 0, stream>>>(x, pooled);
    k2_gates<<<B_, 64, 0, stream>>>(pooled, w1, b1, wk, wi, wo, wn,
                                    kr, inc, outc, nums);
    k3_wgen<<<256, 256, 0, stream>>>(cw, kr, inc, outc, nums, W2);
    k4_conv<<<512, 512, 0, stream>>>(x, W2, out);
}

// Round 7
// 192.186 us; speedup vs baseline: 1.0038x; 1.0038x over previous
//
#include <hip/hip_runtime.h>
#include <hip/hip_bf16.h>
#include <math.h>

#define B_   32
#define CI   256
#define CO   256
#define KW   7
#define NW   8
#define SQD  8
#define L_   4096

typedef __attribute__((ext_vector_type(8))) __bf16 bf16x8;
typedef __attribute__((ext_vector_type(4))) __bf16 bf16x4;
typedef __attribute__((ext_vector_type(4))) float  f32x4;

static __device__ __forceinline__ unsigned short f2bf(float f) {
    unsigned int u = __builtin_bit_cast(unsigned int, f);
    u += 0x7FFFu + ((u >> 16) & 1u);
    return (unsigned short)(u >> 16);
}
// native-cast pack: compiler emits v_cvt_pk_bf16_f32
static __device__ __forceinline__ uint2 pack4bf(float a, float b, float c, float d) {
    bf16x4 v;
    v[0] = (__bf16)a; v[1] = (__bf16)b; v[2] = (__bf16)c; v[3] = (__bf16)d;
    return __builtin_bit_cast(uint2, v);
}

// ---------------------------------------------------------------------------
// k1: mean over L (deterministic). One block per (b,i) row.
// ---------------------------------------------------------------------------
__global__ __launch_bounds__(256) void k1_mean(
        const float* __restrict__ x, float* __restrict__ pooled) {
    int row = blockIdx.x;                       // b*CI + i
    const float* p = x + (size_t)row * L_;
    int t = threadIdx.x;
    float s = 0.f;
#pragma unroll
    for (int it = 0; it < 4; ++it) {
        float4 v = *(const float4*)(p + (size_t)(t + 256 * it) * 4);
        s += v.x + v.y + v.z + v.w;
    }
    for (int m = 1; m <= 32; m <<= 1) s += __shfl_xor(s, m);
    __shared__ float wsum[4];
    if ((t & 63) == 0) wsum[t >> 6] = s;
    __syncthreads();
    if (t == 0)
        pooled[row] = (wsum[0] + wsum[1] + wsum[2] + wsum[3]) * (1.0f / L_);
}

// ---------------------------------------------------------------------------
// k2: squeeze net + gates. one block (1 wave) per sample.
// ---------------------------------------------------------------------------
__global__ __launch_bounds__(64) void k2_gates(
        const float* __restrict__ pooled,
        const float* __restrict__ w1, const float* __restrict__ b1,
        const float* __restrict__ wk, const float* __restrict__ wi,
        const float* __restrict__ wo, const float* __restrict__ wn,
        float* __restrict__ kr, float* __restrict__ inc,
        float* __restrict__ outc, float* __restrict__ nums)
{
    int b = blockIdx.x, lane = threadIdx.x;
    float pc[4];
#pragma unroll
    for (int j = 0; j < 4; ++j)
        pc[j] = pooled[b * CI + lane + 64 * j];
    float h[SQD];
#pragma unroll
    for (int s = 0; s < SQD; ++s) {
        float ps = 0.f;
#pragma unroll
        for (int j = 0; j < 4; ++j)
            ps += pc[j] * w1[(lane + 64 * j) * SQD + s];
        for (int m = 1; m <= 32; m <<= 1) ps += __shfl_xor(ps, m);
        float z = ps + b1[s];
        h[s] = 0.5f * z * (1.0f + erff(z * 0.70710678118654752f));
    }
    if (lane < KW) {
        float a = 0.f;
#pragma unroll
        for (int s = 0; s < SQD; ++s) a += h[s] * wk[s * KW + lane];
        kr[b * 8 + lane] = 1.0f / (1.0f + expf(-a));
    }
    if (lane < NW) {
        float e[NW]; float mx = -1e30f;
#pragma unroll
        for (int n = 0; n < NW; ++n) {
            float a = 0.f;
#pragma unroll
            for (int s = 0; s < SQD; ++s) a += h[s] * wn[s * NW + n];
            e[n] = a; mx = fmaxf(mx, a);
        }
        float den = 0.f;
#pragma unroll
        for (int n = 0; n < NW; ++n) den += expf(e[n] - mx);
        nums[b * NW + lane] = expf(e[lane] - mx) / den;
    }
#pragma unroll
    for (int j = 0; j < 4; ++j) {
        int c = lane + 64 * j;
        float a = 0.f, o2 = 0.f;
#pragma unroll
        for (int s = 0; s < SQD; ++s) {
            a  += h[s] * wi[s * CI + c];
            o2 += h[s] * wo[s * CO + c];
        }
        inc[b * CI + c]  = 1.0f / (1.0f + expf(-a));
        outc[b * CO + c] = 1.0f / (1.0f + expf(-o2));
    }
}

// ---------------------------------------------------------------------------
// k3: per-sample mixed weights, MFMA layout W2[b][k*8+ic][o][i%32] bf16.
// ---------------------------------------------------------------------------
__global__ __launch_bounds__(256) void k3_wgen(
        const float* __restrict__ cw,
        const float* __restrict__ kr, const float* __restrict__ inc,
        const float* __restrict__ outc, const float* __restrict__ nums,
        unsigned short* __restrict__ W2) {
    __shared__ float s_nums[B_][NW];
    __shared__ float s_kr[B_][KW];
    __shared__ float s_inc[B_][32];
    __shared__ float s_outc[B_][8];
    int t = threadIdx.x;
    int ic = blockIdx.x & 7, o0 = (blockIdx.x >> 3) * 8;
    s_nums[t >> 3][t & 7] = nums[t];
    if (t < B_ * KW) s_kr[t / KW][t % KW] = kr[(t / KW) * 8 + (t % KW)];
    for (int u = t; u < 32 * 32; u += 256) {
        int bb = u >> 5, ii = u & 31;
        s_inc[bb][ii] = inc[bb * CI + ic * 32 + ii];
    }
    for (int u = t; u < 32 * 8; u += 256) {
        int bb = u >> 3, oo = u & 7;
        s_outc[bb][oo] = outc[bb * CO + o0 + oo];
    }
    __syncthreads();
    int ii = t & 31, oo = t >> 5;
    int o = o0 + oo, i = ic * 32 + ii;
    float cwv[KW][NW];
    const float* p = cw + ((size_t)(o * CI + i)) * (KW * NW);
#pragma unroll
    for (int k = 0; k < KW; ++k)
#pragma unroll
        for (int n = 0; n < NW; ++n) cwv[k][n] = p[k * NW + n];
    for (int bb = 0; bb < B_; ++bb) {
        float gio = s_inc[bb][ii] * s_outc[bb][oo];
#pragma unroll
        for (int k = 0; k < KW; ++k) {
            float sk = 0.f;
#pragma unroll
            for (int n = 0; n < NW; ++n) sk += s_nums[bb][n] * cwv[k][n];
            float w = s_kr[bb][k] * gio * sk;
            W2[(((size_t)(bb * KW + k) * 8 + ic) * CO + o) * 32 + ii] = f2bf(w);
        }
    }
}

// ---------------------------------------------------------------------------
// k4: fused transpose + per-sample im2col GEMM (16x16x32 bf16 MFMA).
//     Block = 256 o x 256 l, 1024 threads = 16 waves (4o x 4l),
//     wave = 64o x 64l, acc[4][4] (64 VGPR) -> 4 waves/SIMD at 138 KB LDS.
//     LDS rows pitch 264 bf16 (33 x 16B units); i permuted within row:
//     unit position p = kg*8 + icc holds i = icc*32 + kg*8 + (0..7).
//     Read col = (r + 8*kg + icc) mod 32 -> 2 lanes/bank-group (minimum).
//     Staging writes b128 units, 2-way max. No K-loop barriers; TLP hides
//     latency (4 waves/SIMD).
// ---------------------------------------------------------------------------
__global__ __launch_bounds__(1024) void k4_conv(
        const float* __restrict__ x,             // fp32 [B][CI][L]
        const unsigned short* __restrict__ W2,   // bf16 [B][56][CO][32]
        float* __restrict__ out) {               // [B][CO][L]
    __shared__ __align__(16) unsigned short xs[262 * 264];
    int bid = blockIdx.x;
    int wg  = (bid & 7) * 64 + (bid >> 3);       // XCD-bijective (512%8==0)
    int b = wg >> 4, l0 = (wg & 15) * 256;
    int t = threadIdx.x;
    const float* xb = x + (size_t)b * CI * L_;

    // ---- main staging: rows 3..258 (l = l0..l0+255), units permuted ----
    {
        int P = t >> 4, lam = t & 15;
        int up = P & 31, half = P >> 5;          // up: physical 16B unit 0..31
        int i0 = (up & 7) * 32 + (up >> 3) * 8;  // i-range this unit holds
#pragma unroll
        for (int it = 0; it < 2; ++it) {
            int ch = lam + 16 * (half * 2 + it); // l-chunk 0..63
            const float* src = xb + (size_t)i0 * L_ + l0 + ch * 4;
            float4 f[8];
#pragma unroll
            for (int e = 0; e < 8; ++e)
                f[e] = *(const float4*)(src + (size_t)e * L_);
#pragma unroll
            for (int j = 0; j < 4; ++j) {
                int r = 4 * ch + j + 3;
                uint2 a = pack4bf((&f[0].x)[j], (&f[1].x)[j], (&f[2].x)[j], (&f[3].x)[j]);
                uint2 c = pack4bf((&f[4].x)[j], (&f[5].x)[j], (&f[6].x)[j], (&f[7].x)[j]);
                uint4 w; w.x = a.x; w.y = a.y; w.z = c.x; w.w = c.y;
                *(uint4*)(xs + r * 264 + up * 8) = w;
            }
        }
    }
    // ---- halo: rows 0..2 (l0-3..l0-1) and 259..261 (l0+256..l0+258) ----
    if (t < 128) {
        bool left = t < 64;
        int tt = left ? t : t - 64;
        int i0 = tt * 4;                         // 4 consecutive i, same unit
        int gl4 = left ? l0 - 4 : l0 + 256;
        bool ok = left ? (l0 > 0) : (l0 + 256 < L_);
        float4 f[4];
#pragma unroll
        for (int d = 0; d < 4; ++d)
            f[d] = ok ? *(const float4*)(xb + (size_t)(i0 + d) * L_ + gl4)
                      : make_float4(0.f, 0.f, 0.f, 0.f);
        // physical elem offset within row for i0: p = kg*8+icc, e0 = i0&7
        int eo = ((tt >> 1) & 3) * 64 + (tt >> 3) * 8 + (tt & 1) * 4;
#pragma unroll
        for (int j = 0; j < 4; ++j) {
            if (left && j == 0) continue;
            if (!left && j == 3) continue;
            int r = left ? (j - 1) : (259 + j);
            uint2 w = pack4bf((&f[0].x)[j], (&f[1].x)[j], (&f[2].x)[j], (&f[3].x)[j]);
            *(uint2*)(xs + r * 264 + eo) = w;
        }
    }
    __syncthreads();

    int lane = t & 63, wid = t >> 6;
    int o_base = (wid & 3) * 64;                 // 4 o-waves x 64
    int l_wave = (wid >> 2) * 64;                // 4 l-waves x 64
    int ml = lane & 15, kg = lane >> 4;

    f32x4 acc[4][4];
#pragma unroll
    for (int a = 0; a < 4; ++a)
#pragma unroll
        for (int c = 0; c < 4; ++c) acc[a][c] = (f32x4){0.f, 0.f, 0.f, 0.f};

    const unsigned short* wA = W2 + (size_t)b * (56 * CO * 32)
                               + (o_base + ml) * 32 + kg * 8;
    const unsigned short* xB = xs + (l_wave + ml) * 264 + kg * 64;

    for (int k = 0; k < KW; ++k) {
#pragma unroll
        for (int icc = 0; icc < 8; ++icc) {
            int S = k * 8 + icc;
            bf16x8 AF[4], BF[4];
#pragma unroll
            for (int mt = 0; mt < 4; ++mt)
                AF[mt] = *(const bf16x8*)(wA + (size_t)S * (CO * 32) + mt * 16 * 32);
#pragma unroll
            for (int nt = 0; nt < 4; ++nt)
                BF[nt] = *(const bf16x8*)(xB + (nt * 16 + k) * 264 + icc * 8);
            __builtin_amdgcn_s_setprio(1);
#pragma unroll
            for (int mt = 0; mt < 4; ++mt)
#pragma unroll
                for (int nt = 0; nt < 4; ++nt)
                    acc[mt][nt] = __builtin_amdgcn_mfma_f32_16x16x32_bf16(
                        AF[mt], BF[nt], acc[mt][nt], 0, 0, 0);
            __builtin_amdgcn_s_setprio(0);
        }
    }

    // epilogue: D row(o)=(lane>>4)*4+q, col(l)=lane&15
#pragma unroll
    for (int mt = 0; mt < 4; ++mt) {
        int o = o_base + mt * 16 + kg * 4;
#pragma unroll
        for (int nt = 0; nt < 4; ++nt) {
            int l = l0 + l_wave + nt * 16 + ml;
            float* po = out + ((size_t)(b * CO + o)) * L_ + l;
#pragma unroll
            for (int q = 0; q < 4; ++q)
                po[(size_t)q * L_] = acc[mt][nt][q];
        }
    }
}

// ---------------------------------------------------------------------------
extern "C" void kernel_launch(void* const* d_in, const int* in_sizes, int n_in,
                              void* d_out, int out_size, void* d_ws, size_t ws_size,
                              hipStream_t stream) {
    const float* x  = (const float*)d_in[0];
    const float* cw = (const float*)d_in[1];
    const float* w1 = (const float*)d_in[2];
    const float* b1 = (const float*)d_in[3];
    const float* wk = (const float*)d_in[4];
    const float* wi = (const float*)d_in[5];
    const float* wo = (const float*)d_in[6];
    const float* wn = (const float*)d_in[7];
    float* out = (float*)d_out;

    char* ws = (char*)d_ws;
    unsigned short* W2 = (unsigned short*)(ws + 0);          // 29360128 B
    float* pooled = (float*)(ws + 29360128);
    float* kr     = (float*)(ws + 29392896);
    float* inc    = (float*)(ws + 29393920);
    float* outc   = (float*)(ws + 29426688);
    float* nums   = (float*)(ws + 29459456);

    k1_mean<<<B_ * CI, 256, 0, stream>>>(x, pooled);
    k2_gates<<<B_, 64, 0, stream>>>(pooled, w1, b1, wk, wi, wo, wn,
                                    kr, inc, outc, nums);
    k3_wgen<<<256, 256, 0, stream>>>(cw, kr, inc, outc, nums, W2);
    k4_conv<<<512, 1024, 0, stream>>>(x, W2, out);
}

// Round 8
// 190.853 us; speedup vs baseline: 1.0108x; 1.0070x over previous
//
#include <hip/hip_runtime.h>
#include <hip/hip_bf16.h>
#include <math.h>

#define B_   32
#define CI   256
#define CO   256
#define KW   7
#define NW   8
#define SQD  8
#define L_   4096

typedef __attribute__((ext_vector_type(8))) __bf16 bf16x8;
typedef __attribute__((ext_vector_type(4))) __bf16 bf16x4;
typedef __attribute__((ext_vector_type(4))) float  f32x4;

static __device__ __forceinline__ unsigned short f2bf(float f) {
    unsigned int u = __builtin_bit_cast(unsigned int, f);
    u += 0x7FFFu + ((u >> 16) & 1u);
    return (unsigned short)(u >> 16);
}
// native-cast pack: compiler emits v_cvt_pk_bf16_f32
static __device__ __forceinline__ uint2 pack4bf(float a, float b, float c, float d) {
    bf16x4 v;
    v[0] = (__bf16)a; v[1] = (__bf16)b; v[2] = (__bf16)c; v[3] = (__bf16)d;
    return __builtin_bit_cast(uint2, v);
}

// ---------------------------------------------------------------------------
// k1: mean over L (deterministic). One block per (b,i) row.
// ---------------------------------------------------------------------------
__global__ __launch_bounds__(256) void k1_mean(
        const float* __restrict__ x, float* __restrict__ pooled) {
    int row = blockIdx.x;                       // b*CI + i
    const float* p = x + (size_t)row * L_;
    int t = threadIdx.x;
    float s = 0.f;
#pragma unroll
    for (int it = 0; it < 4; ++it) {
        float4 v = *(const float4*)(p + (size_t)(t + 256 * it) * 4);
        s += v.x + v.y + v.z + v.w;
    }
    for (int m = 1; m <= 32; m <<= 1) s += __shfl_xor(s, m);
    __shared__ float wsum[4];
    if ((t & 63) == 0) wsum[t >> 6] = s;
    __syncthreads();
    if (t == 0)
        pooled[row] = (wsum[0] + wsum[1] + wsum[2] + wsum[3]) * (1.0f / L_);
}

// ---------------------------------------------------------------------------
// k2: squeeze net + gates. one block (1 wave) per sample.
// ---------------------------------------------------------------------------
__global__ __launch_bounds__(64) void k2_gates(
        const float* __restrict__ pooled,
        const float* __restrict__ w1, const float* __restrict__ b1,
        const float* __restrict__ wk, const float* __restrict__ wi,
        const float* __restrict__ wo, const float* __restrict__ wn,
        float* __restrict__ kr, float* __restrict__ inc,
        float* __restrict__ outc, float* __restrict__ nums)
{
    int b = blockIdx.x, lane = threadIdx.x;
    float pc[4];
#pragma unroll
    for (int j = 0; j < 4; ++j)
        pc[j] = pooled[b * CI + lane + 64 * j];
    float h[SQD];
#pragma unroll
    for (int s = 0; s < SQD; ++s) {
        float ps = 0.f;
#pragma unroll
        for (int j = 0; j < 4; ++j)
            ps += pc[j] * w1[(lane + 64 * j) * SQD + s];
        for (int m = 1; m <= 32; m <<= 1) ps += __shfl_xor(ps, m);
        float z = ps + b1[s];
        h[s] = 0.5f * z * (1.0f + erff(z * 0.70710678118654752f));
    }
    if (lane < KW) {
        float a = 0.f;
#pragma unroll
        for (int s = 0; s < SQD; ++s) a += h[s] * wk[s * KW + lane];
        kr[b * 8 + lane] = 1.0f / (1.0f + expf(-a));
    }
    if (lane < NW) {
        float e[NW]; float mx = -1e30f;
#pragma unroll
        for (int n = 0; n < NW; ++n) {
            float a = 0.f;
#pragma unroll
            for (int s = 0; s < SQD; ++s) a += h[s] * wn[s * NW + n];
            e[n] = a; mx = fmaxf(mx, a);
        }
        float den = 0.f;
#pragma unroll
        for (int n = 0; n < NW; ++n) den += expf(e[n] - mx);
        nums[b * NW + lane] = expf(e[lane] - mx) / den;
    }
#pragma unroll
    for (int j = 0; j < 4; ++j) {
        int c = lane + 64 * j;
        float a = 0.f, o2 = 0.f;
#pragma unroll
        for (int s = 0; s < SQD; ++s) {
            a  += h[s] * wi[s * CI + c];
            o2 += h[s] * wo[s * CO + c];
        }
        inc[b * CI + c]  = 1.0f / (1.0f + expf(-a));
        outc[b * CO + c] = 1.0f / (1.0f + expf(-o2));
    }
}

// ---------------------------------------------------------------------------
// k3: per-sample mixed weights, MFMA layout W2[b][k*8+ic][o][i%32] bf16.
// ---------------------------------------------------------------------------
__global__ __launch_bounds__(256) void k3_wgen(
        const float* __restrict__ cw,
        const float* __restrict__ kr, const float* __restrict__ inc,
        const float* __restrict__ outc, const float* __restrict__ nums,
        unsigned short* __restrict__ W2) {
    __shared__ float s_nums[B_][NW];
    __shared__ float s_kr[B_][KW];
    __shared__ float s_inc[B_][32];
    __shared__ float s_outc[B_][8];
    int t = threadIdx.x;
    int ic = blockIdx.x & 7, o0 = (blockIdx.x >> 3) * 8;
    s_nums[t >> 3][t & 7] = nums[t];
    if (t < B_ * KW) s_kr[t / KW][t % KW] = kr[(t / KW) * 8 + (t % KW)];
    for (int u = t; u < 32 * 32; u += 256) {
        int bb = u >> 5, ii = u & 31;
        s_inc[bb][ii] = inc[bb * CI + ic * 32 + ii];
    }
    for (int u = t; u < 32 * 8; u += 256) {
        int bb = u >> 3, oo = u & 7;
        s_outc[bb][oo] = outc[bb * CO + o0 + oo];
    }
    __syncthreads();
    int ii = t & 31, oo = t >> 5;
    int o = o0 + oo, i = ic * 32 + ii;
    float cwv[KW][NW];
    const float* p = cw + ((size_t)(o * CI + i)) * (KW * NW);
#pragma unroll
    for (int k = 0; k < KW; ++k)
#pragma unroll
        for (int n = 0; n < NW; ++n) cwv[k][n] = p[k * NW + n];
    for (int bb = 0; bb < B_; ++bb) {
        float gio = s_inc[bb][ii] * s_outc[bb][oo];
#pragma unroll
        for (int k = 0; k < KW; ++k) {
            float sk = 0.f;
#pragma unroll
            for (int n = 0; n < NW; ++n) sk += s_nums[bb][n] * cwv[k][n];
            float w = s_kr[bb][k] * gio * sk;
            W2[(((size_t)(bb * KW + k) * 8 + ic) * CO + o) * 32 + ii] = f2bf(w);
        }
    }
}

// ---------------------------------------------------------------------------
// k4: fused transpose + per-sample im2col GEMM (16x16x32 bf16 MFMA).
//     Block = 256 o x 128 l, 512 threads = 8 waves (4o x 2l),
//     wave = 64o x 64l, acc[4][4].
//     LDS: xs[134][264] bf16 (70.7 KB) -> 2 blocks/CU (stage/compute
//     overlap across blocks), 4 waves/SIMD.
//     Layout: pitch 264 bf16 = 33 x 16B units/row, i LINEAR within row
//     (unit u holds i = 8u..8u+7). Read unit = 33r + 4*icc + kg: kg-lanes
//     land on adjacent units (different bank groups) - measured-best (r2).
//     Staging: b128 writes, thread u=t>>4 packs 8 i x 4 l per uint4.
//     __launch_bounds__(512,4): VGPR cap 128 (r7's 56-VGPR strangle fix).
// ---------------------------------------------------------------------------
__global__ __launch_bounds__(512, 4) void k4_conv(
        const float* __restrict__ x,             // fp32 [B][CI][L]
        const unsigned short* __restrict__ W2,   // bf16 [B][56][CO][32]
        float* __restrict__ out) {               // [B][CO][L]
    __shared__ __align__(16) unsigned short xs[134 * 264];
    int bid = blockIdx.x;
    int wg  = (bid & 7) * 128 + (bid >> 3);      // XCD-bijective (1024%8==0)
    int b = wg >> 5, l0 = (wg & 31) * 128;
    int t = threadIdx.x;
    const float* xb = x + (size_t)b * CI * L_;

    // ---- main staging: rows 3..130 (l = l0..l0+127), i linear ----
    {
        int u = t >> 4;                          // 16B unit 0..31 = i 8u..8u+7
        int lam = t & 15;
        int i0 = u * 8;
#pragma unroll
        for (int it = 0; it < 2; ++it) {
            int ch = lam + 16 * it;              // l-chunk 0..31 (4 l each)
            const float* src = xb + (size_t)i0 * L_ + l0 + ch * 4;
            float4 f[8];
#pragma unroll
            for (int e = 0; e < 8; ++e)
                f[e] = *(const float4*)(src + (size_t)e * L_);
#pragma unroll
            for (int j = 0; j < 4; ++j) {
                int r = ch * 4 + j + 3;
                uint2 a = pack4bf((&f[0].x)[j], (&f[1].x)[j], (&f[2].x)[j], (&f[3].x)[j]);
                uint2 c = pack4bf((&f[4].x)[j], (&f[5].x)[j], (&f[6].x)[j], (&f[7].x)[j]);
                uint4 w; w.x = a.x; w.y = a.y; w.z = c.x; w.w = c.y;
                *(uint4*)(xs + r * 264 + u * 8) = w;
            }
        }
    }
    // ---- halo: rows 0..2 (gl=l0-3..l0-1), 131..133 (gl=l0+128..l0+130) ----
    if (t < 192) {
        int h = t >> 5, u = t & 31;
        int r = (h < 3) ? h : (128 + h);
        int gl = l0 - 3 + r;
        bool ok = (gl >= 0 && gl < L_);
        float f[8];
#pragma unroll
        for (int e = 0; e < 8; ++e)
            f[e] = ok ? xb[(size_t)(u * 8 + e) * L_ + gl] : 0.f;
        uint2 a = pack4bf(f[0], f[1], f[2], f[3]);
        uint2 c = pack4bf(f[4], f[5], f[6], f[7]);
        uint4 w; w.x = a.x; w.y = a.y; w.z = c.x; w.w = c.y;
        *(uint4*)(xs + r * 264 + u * 8) = w;
    }
    __syncthreads();

    int lane = t & 63, wid = t >> 6;
    int o_base = (wid & 3) * 64;                 // 4 o-waves x 64
    int l_wave = (wid >> 2) * 64;                // 2 l-waves x 64
    int ml = lane & 15, kg = lane >> 4;

    f32x4 acc[4][4];
#pragma unroll
    for (int a = 0; a < 4; ++a)
#pragma unroll
        for (int c = 0; c < 4; ++c) acc[a][c] = (f32x4){0.f, 0.f, 0.f, 0.f};

    const unsigned short* wA = W2 + (size_t)b * (56 * CO * 32)
                               + (o_base + ml) * 32 + kg * 8;
    const unsigned short* xB = xs + (l_wave + ml) * 264 + kg * 8;

    for (int k = 0; k < KW; ++k) {
#pragma unroll
        for (int icc = 0; icc < 8; ++icc) {
            int S = k * 8 + icc;
            bf16x8 AF[4], BF[4];
#pragma unroll
            for (int mt = 0; mt < 4; ++mt)
                AF[mt] = *(const bf16x8*)(wA + (size_t)S * (CO * 32) + mt * 16 * 32);
#pragma unroll
            for (int nt = 0; nt < 4; ++nt)
                BF[nt] = *(const bf16x8*)(xB + (nt * 16 + k) * 264 + icc * 32);
            __builtin_amdgcn_s_setprio(1);
#pragma unroll
            for (int mt = 0; mt < 4; ++mt)
#pragma unroll
                for (int nt = 0; nt < 4; ++nt)
                    acc[mt][nt] = __builtin_amdgcn_mfma_f32_16x16x32_bf16(
                        AF[mt], BF[nt], acc[mt][nt], 0, 0, 0);
            __builtin_amdgcn_s_setprio(0);
        }
    }

    // epilogue: D row(o)=(lane>>4)*4+q, col(l)=lane&15
#pragma unroll
    for (int mt = 0; mt < 4; ++mt) {
        int o = o_base + mt * 16 + kg * 4;
#pragma unroll
        for (int nt = 0; nt < 4; ++nt) {
            int l = l0 + l_wave + nt * 16 + ml;
            float* po = out + ((size_t)(b * CO + o)) * L_ + l;
#pragma unroll
            for (int q = 0; q < 4; ++q)
                po[(size_t)q * L_] = acc[mt][nt][q];
        }
    }
}

// ---------------------------------------------------------------------------
extern "C" void kernel_launch(void* const* d_in, const int* in_sizes, int n_in,
                              void* d_out, int out_size, void* d_ws, size_t ws_size,
                              hipStream_t stream) {
    const float* x  = (const float*)d_in[0];
    const float* cw = (const float*)d_in[1];
    const float* w1 = (const float*)d_in[2];
    const float* b1 = (const float*)d_in[3];
    const float* wk = (const float*)d_in[4];
    const float* wi = (const float*)d_in[5];
    const float* wo = (const float*)d_in[6];
    const float* wn = (const float*)d_in[7];
    float* out = (float*)d_out;

    char* ws = (char*)d_ws;
    unsigned short* W2 = (unsigned short*)(ws + 0);          // 29360128 B
    float* pooled = (float*)(ws + 29360128);
    float* kr     = (float*)(ws + 29392896);
    float* inc    = (float*)(ws + 29393920);
    float* outc   = (float*)(ws + 29426688);
    float* nums   = (float*)(ws + 29459456);

    k1_mean<<<B_ * CI, 256, 0, stream>>>(x, pooled);
    k2_gates<<<B_, 64, 0, stream>>>(pooled, w1, b1, wk, wi, wo, wn,
                                    kr, inc, outc, nums);
    k3_wgen<<<256, 256, 0, stream>>>(cw, kr, inc, outc, nums, W2);
    k4_conv<<<1024, 512, 0, stream>>>(x, W2, out);
}

// Round 9
// 167.963 us; speedup vs baseline: 1.1486x; 1.1363x over previous
//
#include <hip/hip_runtime.h>
#include <hip/hip_bf16.h>
#include <math.h>

#define B_   32
#define CI   256
#define CO   256
#define KW   7
#define NW   8
#define SQD  8
#define L_   4096

typedef __attribute__((ext_vector_type(8))) __bf16 bf16x8;
typedef __attribute__((ext_vector_type(4))) __bf16 bf16x4;
typedef __attribute__((ext_vector_type(4))) float  f32x4;

static __device__ __forceinline__ unsigned short f2bf(float f) {
    unsigned int u = __builtin_bit_cast(unsigned int, f);
    u += 0x7FFFu + ((u >> 16) & 1u);
    return (unsigned short)(u >> 16);
}
// native-cast pack: compiler emits v_cvt_pk_bf16_f32
static __device__ __forceinline__ uint2 pack4bf(float a, float b, float c, float d) {
    bf16x4 v;
    v[0] = (__bf16)a; v[1] = (__bf16)b; v[2] = (__bf16)c; v[3] = (__bf16)d;
    return __builtin_bit_cast(uint2, v);
}

// ---------------------------------------------------------------------------
// k1: mean over L (deterministic). One block per (b,i) row.
// ---------------------------------------------------------------------------
__global__ __launch_bounds__(256) void k1_mean(
        const float* __restrict__ x, float* __restrict__ pooled) {
    int row = blockIdx.x;                       // b*CI + i
    const float* p = x + (size_t)row * L_;
    int t = threadIdx.x;
    float s = 0.f;
#pragma unroll
    for (int it = 0; it < 4; ++it) {
        float4 v = *(const float4*)(p + (size_t)(t + 256 * it) * 4);
        s += v.x + v.y + v.z + v.w;
    }
    for (int m = 1; m <= 32; m <<= 1) s += __shfl_xor(s, m);
    __shared__ float wsum[4];
    if ((t & 63) == 0) wsum[t >> 6] = s;
    __syncthreads();
    if (t == 0)
        pooled[row] = (wsum[0] + wsum[1] + wsum[2] + wsum[3]) * (1.0f / L_);
}

// ---------------------------------------------------------------------------
// k2: squeeze net + gates. one block (1 wave) per sample.
// ---------------------------------------------------------------------------
__global__ __launch_bounds__(64) void k2_gates(
        const float* __restrict__ pooled,
        const float* __restrict__ w1, const float* __restrict__ b1,
        const float* __restrict__ wk, const float* __restrict__ wi,
        const float* __restrict__ wo, const float* __restrict__ wn,
        float* __restrict__ kr, float* __restrict__ inc,
        float* __restrict__ outc, float* __restrict__ nums)
{
    int b = blockIdx.x, lane = threadIdx.x;
    float pc[4];
#pragma unroll
    for (int j = 0; j < 4; ++j)
        pc[j] = pooled[b * CI + lane + 64 * j];
    float h[SQD];
#pragma unroll
    for (int s = 0; s < SQD; ++s) {
        float ps = 0.f;
#pragma unroll
        for (int j = 0; j < 4; ++j)
            ps += pc[j] * w1[(lane + 64 * j) * SQD + s];
        for (int m = 1; m <= 32; m <<= 1) ps += __shfl_xor(ps, m);
        float z = ps + b1[s];
        h[s] = 0.5f * z * (1.0f + erff(z * 0.70710678118654752f));
    }
    if (lane < KW) {
        float a = 0.f;
#pragma unroll
        for (int s = 0; s < SQD; ++s) a += h[s] * wk[s * KW + lane];
        kr[b * 8 + lane] = 1.0f / (1.0f + expf(-a));
    }
    if (lane < NW) {
        float e[NW]; float mx = -1e30f;
#pragma unroll
        for (int n = 0; n < NW; ++n) {
            float a = 0.f;
#pragma unroll
            for (int s = 0; s < SQD; ++s) a += h[s] * wn[s * NW + n];
            e[n] = a; mx = fmaxf(mx, a);
        }
        float den = 0.f;
#pragma unroll
        for (int n = 0; n < NW; ++n) den += expf(e[n] - mx);
        nums[b * NW + lane] = expf(e[lane] - mx) / den;
    }
#pragma unroll
    for (int j = 0; j < 4; ++j) {
        int c = lane + 64 * j;
        float a = 0.f, o2 = 0.f;
#pragma unroll
        for (int s = 0; s < SQD; ++s) {
            a  += h[s] * wi[s * CI + c];
            o2 += h[s] * wo[s * CO + c];
        }
        inc[b * CI + c]  = 1.0f / (1.0f + expf(-a));
        outc[b * CO + c] = 1.0f / (1.0f + expf(-o2));
    }
}

// ---------------------------------------------------------------------------
// k3: per-sample mixed weights, MFMA layout W2[b][k*8+ic][o][i%32] bf16.
// ---------------------------------------------------------------------------
__global__ __launch_bounds__(256) void k3_wgen(
        const float* __restrict__ cw,
        const float* __restrict__ kr, const float* __restrict__ inc,
        const float* __restrict__ outc, const float* __restrict__ nums,
        unsigned short* __restrict__ W2) {
    __shared__ float s_nums[B_][NW];
    __shared__ float s_kr[B_][KW];
    __shared__ float s_inc[B_][32];
    __shared__ float s_outc[B_][8];
    int t = threadIdx.x;
    int ic = blockIdx.x & 7, o0 = (blockIdx.x >> 3) * 8;
    s_nums[t >> 3][t & 7] = nums[t];
    if (t < B_ * KW) s_kr[t / KW][t % KW] = kr[(t / KW) * 8 + (t % KW)];
    for (int u = t; u < 32 * 32; u += 256) {
        int bb = u >> 5, ii = u & 31;
        s_inc[bb][ii] = inc[bb * CI + ic * 32 + ii];
    }
    for (int u = t; u < 32 * 8; u += 256) {
        int bb = u >> 3, oo = u & 7;
        s_outc[bb][oo] = outc[bb * CO + o0 + oo];
    }
    __syncthreads();
    int ii = t & 31, oo = t >> 5;
    int o = o0 + oo, i = ic * 32 + ii;
    float cwv[KW][NW];
    const float* p = cw + ((size_t)(o * CI + i)) * (KW * NW);
#pragma unroll
    for (int k = 0; k < KW; ++k)
#pragma unroll
        for (int n = 0; n < NW; ++n) cwv[k][n] = p[k * NW + n];
    for (int bb = 0; bb < B_; ++bb) {
        float gio = s_inc[bb][ii] * s_outc[bb][oo];
#pragma unroll
        for (int k = 0; k < KW; ++k) {
            float sk = 0.f;
#pragma unroll
            for (int n = 0; n < NW; ++n) sk += s_nums[bb][n] * cwv[k][n];
            float w = s_kr[bb][k] * gio * sk;
            W2[(((size_t)(bb * KW + k) * 8 + ic) * CO + o) * 32 + ii] = f2bf(w);
        }
    }
}

// ---------------------------------------------------------------------------
// k4: fused transpose + per-sample im2col GEMM (16x16x32 bf16 MFMA).
//     Block = 256 o x 128 l, 256 threads = 4 waves (o-split),
//     wave = 64 o x 128 l, acc[4][8] (AGPR) + manual 2-deep pipeline (r5's
//     43%-MfmaUtil structure).
//     LDS: xs[134][264] bf16 = 70.8 KB -> 2 blocks/CU: block A's compute
//     covers block B's serial staging (the overlap r5 lacked at 134 KB).
//     B-layout: pitch 264, i LINEAR in row (measured-best ~4 cyc/read, r2/r8)
//     Grid 1024 = 32 samples x 32 l-tiles, XCD-bijective swizzle.
// ---------------------------------------------------------------------------
__global__ __launch_bounds__(256, 2) void k4_conv(
        const float* __restrict__ x,             // fp32 [B][CI][L]
        const unsigned short* __restrict__ W2,   // bf16 [B][56][CO][32]
        float* __restrict__ out) {               // [B][CO][L]
    __shared__ __align__(16) unsigned short xs[134 * 264];
    int bid = blockIdx.x;
    int wg  = (bid & 7) * 128 + (bid >> 3);      // XCD-bijective (1024%8==0)
    int b = wg >> 5, l0 = (wg & 31) * 128;
    int t = threadIdx.x;
    const float* xb = x + (size_t)b * CI * L_;

    // ---- main staging: rows 3..130 (l = l0..l0+127), i linear ----
    {
        int u = t >> 3;                          // 16B unit 0..31 = i 8u..8u+7
        int lam = t & 7;
        int i0 = u * 8;
#pragma unroll
        for (int it = 0; it < 4; ++it) {
            int ch = lam + 8 * it;               // l-chunk 0..31 (4 l each)
            const float* src = xb + (size_t)i0 * L_ + l0 + ch * 4;
            float4 f[8];
#pragma unroll
            for (int e = 0; e < 8; ++e)
                f[e] = *(const float4*)(src + (size_t)e * L_);
#pragma unroll
            for (int j = 0; j < 4; ++j) {
                int r = ch * 4 + j + 3;
                uint2 a = pack4bf((&f[0].x)[j], (&f[1].x)[j], (&f[2].x)[j], (&f[3].x)[j]);
                uint2 c = pack4bf((&f[4].x)[j], (&f[5].x)[j], (&f[6].x)[j], (&f[7].x)[j]);
                uint4 w; w.x = a.x; w.y = a.y; w.z = c.x; w.w = c.y;
                *(uint4*)(xs + r * 264 + u * 8) = w;
            }
        }
    }
    // ---- halo: rows 0..2 (gl=l0-3..l0-1), 131..133 (gl=l0+128..l0+130) ----
    if (t < 192) {
        int h = t >> 5, u = t & 31;
        int r = (h < 3) ? h : (128 + h);
        int gl = l0 - 3 + r;
        bool ok = (gl >= 0 && gl < L_);
        float f[8];
#pragma unroll
        for (int e = 0; e < 8; ++e)
            f[e] = ok ? xb[(size_t)(u * 8 + e) * L_ + gl] : 0.f;
        uint2 a = pack4bf(f[0], f[1], f[2], f[3]);
        uint2 c = pack4bf(f[4], f[5], f[6], f[7]);
        uint4 w; w.x = a.x; w.y = a.y; w.z = c.x; w.w = c.y;
        *(uint4*)(xs + r * 264 + u * 8) = w;
    }
    __syncthreads();

    int lane = t & 63, wid = t >> 6;
    int o_base = wid * 64;                       // 4 o-waves x 64
    int ml = lane & 15, kg = lane >> 4;

    f32x4 acc[4][8];
#pragma unroll
    for (int a = 0; a < 4; ++a)
#pragma unroll
        for (int c = 0; c < 8; ++c) acc[a][c] = (f32x4){0.f, 0.f, 0.f, 0.f};

    const unsigned short* wA = W2 + (size_t)b * (56 * CO * 32)
                               + (o_base + ml) * 32 + kg * 8;
    const unsigned short* xB = xs + (size_t)ml * 264 + kg * 8;

    auto LOADF = [&](bf16x8 (&AF)[4], bf16x8 (&BF)[8], int S) {
        int k_ = S >> 3, icc_ = S & 7;
#pragma unroll
        for (int mt = 0; mt < 4; ++mt)
            AF[mt] = *(const bf16x8*)(wA + (size_t)S * (CO * 32) + mt * 16 * 32);
#pragma unroll
        for (int nt = 0; nt < 8; ++nt)
            BF[nt] = *(const bf16x8*)(xB + (nt * 16 + k_) * 264 + icc_ * 32);
    };
    auto DOMFMA = [&](bf16x8 (&AF)[4], bf16x8 (&BF)[8]) {
        __builtin_amdgcn_s_setprio(1);
#pragma unroll
        for (int mt = 0; mt < 4; ++mt)
#pragma unroll
            for (int nt = 0; nt < 8; ++nt)
                acc[mt][nt] = __builtin_amdgcn_mfma_f32_16x16x32_bf16(
                    AF[mt], BF[nt], acc[mt][nt], 0, 0, 0);
        __builtin_amdgcn_s_setprio(0);
    };

    bf16x8 afA[4], bfA[8], afB[4], bfB[8];
    LOADF(afA, bfA, 0);
    for (int s = 0; s < 56; s += 2) {
        LOADF(afB, bfB, s + 1);
        DOMFMA(afA, bfA);
        if (s + 2 < 56) LOADF(afA, bfA, s + 2);
        DOMFMA(afB, bfB);
    }

    // epilogue: D row(o)=(lane>>4)*4+q, col(l)=lane&15
#pragma unroll
    for (int mt = 0; mt < 4; ++mt) {
        int o = o_base + mt * 16 + kg * 4;
#pragma unroll
        for (int nt = 0; nt < 8; ++nt) {
            int l = l0 + nt * 16 + ml;
            float* po = out + ((size_t)(b * CO + o)) * L_ + l;
#pragma unroll
            for (int q = 0; q < 4; ++q)
                po[(size_t)q * L_] = acc[mt][nt][q];
        }
    }
}

// ---------------------------------------------------------------------------
extern "C" void kernel_launch(void* const* d_in, const int* in_sizes, int n_in,
                              void* d_out, int out_size, void* d_ws, size_t ws_size,
                              hipStream_t stream) {
    const float* x  = (const float*)d_in[0];
    const float* cw = (const float*)d_in[1];
    const float* w1 = (const float*)d_in[2];
    const float* b1 = (const float*)d_in[3];
    const float* wk = (const float*)d_in[4];
    const float* wi = (const float*)d_in[5];
    const float* wo = (const float*)d_in[6];
    const float* wn = (const float*)d_in[7];
    float* out = (float*)d_out;

    char* ws = (char*)d_ws;
    unsigned short* W2 = (unsigned short*)(ws + 0);          // 29360128 B
    float* pooled = (float*)(ws + 29360128);
    float* kr     = (float*)(ws + 29392896);
    float* inc    = (float*)(ws + 29393920);
    float* outc   = (float*)(ws + 29426688);
    float* nums   = (float*)(ws + 29459456);

    k1_mean<<<B_ * CI, 256, 0, stream>>>(x, pooled);
    k2_gates<<<B_, 64, 0, stream>>>(pooled, w1, b1, wk, wi, wo, wn,
                                    kr, inc, outc, nums);
    k3_wgen<<<256, 256, 0, stream>>>(cw, kr, inc, outc, nums, W2);
    k4_conv<<<1024, 256, 0, stream>>>(x, W2, out);
}